// Round 3
// baseline (115.479 us; speedup 1.0000x reference)
//
#include <hip/hip_runtime.h>
#include <hip/hip_cooperative_groups.h>
#include <math.h>

namespace cg = cooperative_groups;

#define NG 2048
#define IMG_W 128
#define IMG_H 128
#define NPIX (IMG_W * IMG_H)
#define ALPHA_MIN (1.0f / 255.0f)
#define NSEG 4
#define SEG (NG / NSEG)  // 512 gaussians per z-segment

// ws layout: float aos[2048][12] z-sorted params:
//   px, py, rc2, A, B, C, op, cr, cg, cb, pad, pad

// ---------------------------------------------------------------------------
// Single cooperative kernel: 256 blocks x 256 threads (1 block/CU).
// Phase 1: stable ranks (z asc, ties by index == stable argsort) + projection
//          + z-sorted AoS scatter.  Phase 2 (after grid.sync): render.
__global__ void __launch_bounds__(256) fused_kernel(const float* __restrict__ means,
                                                    const float* __restrict__ colors,
                                                    const float* __restrict__ opac,
                                                    const float* __restrict__ cov3,
                                                    const float* __restrict__ bgp,
                                                    float* __restrict__ out,
                                                    float* __restrict__ aos) {
    __shared__ float zs[NG];          // 8 KB: all z values
    __shared__ int   rankv[8];
    __shared__ float part[NSEG][4][64];

    const int t = threadIdx.x;
    const int b = blockIdx.x;

    // ---- Phase 1a: stable rank of this block's 8 gaussians -----------------
    for (int k = t; k < NG; k += 256) zs[k] = means[k * 3 + 2];
    __syncthreads();

    const int gi  = b * 8 + (t >> 5);   // gaussian handled by this 32-thread group
    const int sub = t & 31;
    const float zi = zs[gi];
    int cnt = 0;
    const int j0 = sub * 64;
#pragma unroll 8
    for (int j = j0; j < j0 + 64; ++j) {
        const float zj = zs[j];
        cnt += (zj < zi || (zj == zi && j < gi)) ? 1 : 0;
    }
#pragma unroll
    for (int d = 16; d; d >>= 1) cnt += __shfl_down(cnt, d, 32);
    if (sub == 0) rankv[t >> 5] = cnt;
    __syncthreads();

    // ---- Phase 1b: projection/conic (f64 keeps ceil() boundaries exact) ----
    if (t < 8) {
        const int i = b * 8 + t;
        const double x = means[i * 3 + 0];
        const double y = means[i * 3 + 1];
        const double z = means[i * 3 + 2];
        const double inv_z = 1.0 / z;
        const double fx = 128.0, fy = 128.0, lim = 0.65;  // W/(2*tanfov), 1.3*tanfov
        const double px = fx * x * inv_z + 64.0;
        const double py = fy * y * inv_z + 64.0;
        double tx = x * inv_z; tx = fmin(fmax(tx, -lim), lim); tx *= z;
        double ty = y * inv_z; ty = fmin(fmax(ty, -lim), lim); ty *= z;
        const double xx = cov3[i * 6 + 0], xy = cov3[i * 6 + 1], xz = cov3[i * 6 + 2];
        const double yy = cov3[i * 6 + 3], yz = cov3[i * 6 + 4], zz = cov3[i * 6 + 5];
        const double J00 = fx * inv_z, J02 = -fx * tx * inv_z * inv_z;
        const double J11 = fy * inv_z, J12 = -fy * ty * inv_z * inv_z;
        const double M00 = J00 * xx + J02 * xz;
        const double M01 = J00 * xy + J02 * yz;
        const double M02 = J00 * xz + J02 * zz;
        const double M11 = J11 * yy + J12 * yz;
        const double M12 = J11 * yz + J12 * zz;
        const double a = M00 * J00 + M02 * J02 + 0.3;
        const double bb = M01 * J11 + M02 * J12;  // cov2[0,1]
        const double c = M11 * J11 + M12 * J12 + 0.3;
        const double det = a * c - bb * bb;
        const double inv_det = 1.0 / det;
        const double mid = 0.5 * (a + c);
        const double lam1 = mid + sqrt(fmax(0.1, mid * mid - det));
        const bool valid = (z > 0.2) && (det > 0.0);
        out[3 * NPIX + i] = valid ? (float)ceil(3.0 * sqrt(lam1)) : 0.0f;

        const float op = opac[i];
        // Conservative cull radius^2: outside it alpha < ALPHA_MIN * e^-0.05
        // guaranteed (d^T Sigma^-1 d >= d^2 / lam1, lam1 >= lambda_max).
        float rc2 = -1.0f;
        if (valid) {
            const double L = log(255.0 * (double)op);
            if (L > 0.0) rc2 = (float)(2.0 * (L + 0.05) * lam1 * 1.0001);
        }
        const int r = rankv[t];
        float4* dst = (float4*)(aos + r * 12);
        dst[0] = make_float4((float)px, (float)py, rc2, (float)(c * inv_det));
        dst[1] = make_float4((float)(-bb * inv_det), (float)(a * inv_det), op,
                             colors[i * 3 + 0]);
        dst[2] = make_float4(colors[i * 3 + 1], colors[i * 3 + 2], 0.0f, 0.0f);
    }

    cg::this_grid().sync();

    // ---- Phase 2: render ---------------------------------------------------
    const int lane = t & 63;
    const int wave = t >> 6;
    const int tile_x = (b & 15) * 8;
    const int tile_y = (b >> 4) * 8;
    const float pxf = (float)(tile_x + (lane & 7));
    const float pyf = (float)(tile_y + (lane >> 3));
    const float tx0 = (float)tile_x, tx1 = (float)(tile_x + 7);
    const float ty0 = (float)tile_y, ty1 = (float)(tile_y + 7);

    const float4* __restrict__ av = (const float4*)aos;

    float T = 1.0f, accr = 0.0f, accg = 0.0f, accb = 0.0f;

    int g = wave * SEG + lane;
    float4 a0 = av[g * 3 + 0];
    float4 a1 = av[g * 3 + 1];
    float4 a2 = av[g * 3 + 2];

#define RL(x) __int_as_float(__builtin_amdgcn_readlane(__float_as_int(x), j))
    for (int c = 0; c < SEG / 64; ++c) {
        float4 b0, b1, b2;
        if (c + 1 < SEG / 64) {           // prefetch next chunk
            const int gn = (g + 64) * 3;
            b0 = av[gn + 0]; b1 = av[gn + 1]; b2 = av[gn + 2];
        }
        // tile-rect vs cull-circle test for this lane's gaussian
        const float ddx = fmaxf(fmaxf(tx0 - a0.x, a0.x - tx1), 0.0f);
        const float ddy = fmaxf(fmaxf(ty0 - a0.y, a0.y - ty1), 0.0f);
        unsigned long long m = __ballot(ddx * ddx + ddy * ddy <= a0.z);
        while (m) {
            const int j = __builtin_ctzll(m);
            m &= (m - 1);
            const float cx = RL(a0.x), cy = RL(a0.y);
            const float A = RL(a0.w), B = RL(a1.x), C = RL(a1.y);
            const float op = RL(a1.z);
            const float cr = RL(a1.w), cgc = RL(a2.x), cb = RL(a2.y);
            const float dx = cx - pxf, dy = cy - pyf;
            const float power = -0.5f * (A * dx * dx + C * dy * dy) - B * dx * dy;
            const float alpha = fminf(0.99f, op * __expf(power));
            const bool keep = (power <= 0.0f) & (alpha >= ALPHA_MIN);
            const float ae = keep ? alpha : 0.0f;
            const float w = ae * T;
            accr = fmaf(w, cr, accr);
            accg = fmaf(w, cgc, accg);
            accb = fmaf(w, cb, accb);
            T *= (1.0f - ae);
        }
        // whole-wave saturated -> done (residual contribution < 1e-4)
        if (__ballot(T >= 1e-4f) == 0ull) break;
        a0 = b0; a1 = b1; a2 = b2; g += 64;
    }
#undef RL

    // merge the 4 z-segments, front to back:
    //   img = sum_s (prod_{s'<s} T_s') * acc_s ,  T = prod_s T_s  (exact)
    part[wave][0][lane] = accr;
    part[wave][1][lane] = accg;
    part[wave][2][lane] = accb;
    part[wave][3][lane] = T;
    __syncthreads();
    if (wave == 0) {
        float R = part[0][0][lane], G = part[0][1][lane], Bc = part[0][2][lane];
        float Tt = part[0][3][lane];
#pragma unroll
        for (int s = 1; s < NSEG; ++s) {
            R  = fmaf(Tt, part[s][0][lane], R);
            G  = fmaf(Tt, part[s][1][lane], G);
            Bc = fmaf(Tt, part[s][2][lane], Bc);
            Tt *= part[s][3][lane];
        }
        const int pix = (tile_y + (lane >> 3)) * IMG_W + tile_x + (lane & 7);
        out[pix]            = fmaf(Tt, bgp[0], R);
        out[pix + NPIX]     = fmaf(Tt, bgp[1], G);
        out[pix + 2 * NPIX] = fmaf(Tt, bgp[2], Bc);
    }
}

// ---------------------------------------------------------------------------
extern "C" void kernel_launch(void* const* d_in, const int* in_sizes, int n_in,
                              void* d_out, int out_size, void* d_ws, size_t ws_size,
                              hipStream_t stream) {
    const float* means  = (const float*)d_in[0];  // (N,3)
    const float* colors = (const float*)d_in[1];  // (N,3)
    const float* opac   = (const float*)d_in[2];  // (N,1)
    const float* cov3   = (const float*)d_in[3];  // (N,6)
    const float* bg     = (const float*)d_in[4];  // (3,)
    float* out = (float*)d_out;  // img (3*128*128) then radii (2048) as float
    float* aos = (float*)d_ws;

    void* args[] = {(void*)&means, (void*)&colors, (void*)&opac, (void*)&cov3,
                    (void*)&bg, (void*)&out, (void*)&aos};
    hipLaunchCooperativeKernel((void*)fused_kernel, dim3(256), dim3(256),
                               args, 0, stream);
}

// Round 4
// 102.318 us; speedup vs baseline: 1.1286x; 1.1286x over previous
//
#include <hip/hip_runtime.h>
#include <math.h>

#define NG 2048
#define IMG_W 128
#define IMG_H 128
#define NPIX (IMG_W * IMG_H)
#define ALPHA_MIN (1.0f / 255.0f)
#define NSEG 4
#define SEG (NG / NSEG)       // 512 gaussians per z-segment
#define MAGIC 0x13579BDFu     // != 0xAAAAAAAA poison; any init != MAGIC is safe

// ws layout:
//   [0, 96K)   : float aos[2048][12] z-sorted params:
//                px, py, rc2, A, B, C, op, cr, cg, cb, pad, pad
//   [96K, 97K) : uint flags[256] manual grid-barrier flags (init-free)

// ---------------------------------------------------------------------------
// Single REGULAR kernel (cooperative launch cost ~30us as a graph node - R3).
// 256 blocks x 256 threads. Phase 1: stable ranks (z asc, ties by index ==
// stable argsort) + f64 projection/conic + z-sorted AoS scatter. Manual
// init-free grid barrier. Phase 2: per-tile front-to-back compositing.
__global__ void __launch_bounds__(256) fused_kernel(const float* __restrict__ means,
                                                    const float* __restrict__ colors,
                                                    const float* __restrict__ opac,
                                                    const float* __restrict__ cov3,
                                                    const float* __restrict__ bgp,
                                                    float* __restrict__ out,
                                                    float* __restrict__ aos,
                                                    unsigned int* flags) {
    __shared__ float zs[NG];          // 8 KB: all z values
    __shared__ int   rankv[8];
    __shared__ float part[NSEG][4][64];

    const int t = threadIdx.x;
    const int b = blockIdx.x;

    // ---- Phase 1a: stable rank of this block's 8 gaussians -----------------
    for (int k = t; k < NG; k += 256) zs[k] = means[k * 3 + 2];
    __syncthreads();

    const int gi  = b * 8 + (t >> 5);   // gaussian of this 32-thread group
    const int sub = t & 31;
    const float zi = zs[gi];
    int cnt = 0;
    const int j0 = sub * 64;
#pragma unroll 8
    for (int j = j0; j < j0 + 64; ++j) {
        const float zj = zs[j];
        cnt += (zj < zi || (zj == zi && j < gi)) ? 1 : 0;
    }
#pragma unroll
    for (int d = 16; d; d >>= 1) cnt += __shfl_down(cnt, d, 32);
    if (sub == 0) rankv[t >> 5] = cnt;
    __syncthreads();

    // ---- Phase 1b: projection/conic (f64 keeps ceil() boundaries exact) ----
    if (t < 8) {
        const int i = b * 8 + t;
        const double x = means[i * 3 + 0];
        const double y = means[i * 3 + 1];
        const double z = means[i * 3 + 2];
        const double inv_z = 1.0 / z;
        const double fx = 128.0, fy = 128.0, lim = 0.65;  // W/(2*tanfov), 1.3*tanfov
        const double px = fx * x * inv_z + 64.0;
        const double py = fy * y * inv_z + 64.0;
        double tx = x * inv_z; tx = fmin(fmax(tx, -lim), lim); tx *= z;
        double ty = y * inv_z; ty = fmin(fmax(ty, -lim), lim); ty *= z;
        const double xx = cov3[i * 6 + 0], xy = cov3[i * 6 + 1], xz = cov3[i * 6 + 2];
        const double yy = cov3[i * 6 + 3], yz = cov3[i * 6 + 4], zz = cov3[i * 6 + 5];
        const double J00 = fx * inv_z, J02 = -fx * tx * inv_z * inv_z;
        const double J11 = fy * inv_z, J12 = -fy * ty * inv_z * inv_z;
        const double M00 = J00 * xx + J02 * xz;
        const double M01 = J00 * xy + J02 * yz;
        const double M02 = J00 * xz + J02 * zz;
        const double M11 = J11 * yy + J12 * yz;
        const double M12 = J11 * yz + J12 * zz;
        const double a = M00 * J00 + M02 * J02 + 0.3;
        const double bb = M01 * J11 + M02 * J12;  // cov2[0,1]
        const double c = M11 * J11 + M12 * J12 + 0.3;
        const double det = a * c - bb * bb;
        const double inv_det = 1.0 / det;
        const double mid = 0.5 * (a + c);
        const double lam1 = mid + sqrt(fmax(0.1, mid * mid - det));
        const bool valid = (z > 0.2) && (det > 0.0);
        out[3 * NPIX + i] = valid ? (float)ceil(3.0 * sqrt(lam1)) : 0.0f;

        const float op = opac[i];
        // Conservative cull radius^2: outside it alpha < ALPHA_MIN * e^-0.05
        // guaranteed (d^T Sigma^-1 d >= d^2 / lam1, lam1 >= lambda_max).
        float rc2 = -1.0f;
        if (valid) {
            const double L = log(255.0 * (double)op);
            if (L > 0.0) rc2 = (float)(2.0 * (L + 0.05) * lam1 * 1.0001);
        }
        const int r = rankv[t];
        float4* dst = (float4*)(aos + r * 12);
        dst[0] = make_float4((float)px, (float)py, rc2, (float)(c * inv_det));
        dst[1] = make_float4((float)(-bb * inv_det), (float)(a * inv_det), op,
                             colors[i * 3 + 0]);
        dst[2] = make_float4(colors[i * 3 + 1], colors[i * 3 + 2], 0.0f, 0.0f);
    }

    // ---- Manual grid barrier (init-free: any prior flag value != MAGIC) ----
    __syncthreads();                       // block's AoS writes done
    if (t == 0) {
        __threadfence();                   // device-scope release of aos writes
        __hip_atomic_store(&flags[b], MAGIC, __ATOMIC_RELAXED,
                           __HIP_MEMORY_SCOPE_AGENT);
    }
    while (__hip_atomic_load(&flags[t], __ATOMIC_RELAXED,
                             __HIP_MEMORY_SCOPE_AGENT) != MAGIC) {
        __builtin_amdgcn_s_sleep(2);
    }
    __syncthreads();
    __threadfence();                       // acquire before reading remote aos

    // ---- Phase 2: render ---------------------------------------------------
    const int lane = t & 63;
    const int wave = t >> 6;
    const int tile_x = (b & 15) * 8;
    const int tile_y = (b >> 4) * 8;
    const float pxf = (float)(tile_x + (lane & 7));
    const float pyf = (float)(tile_y + (lane >> 3));
    const float tx0 = (float)tile_x, tx1 = (float)(tile_x + 7);
    const float ty0 = (float)tile_y, ty1 = (float)(tile_y + 7);

    const float4* __restrict__ av = (const float4*)aos;

    float T = 1.0f, accr = 0.0f, accg = 0.0f, accb = 0.0f;

    int g = wave * SEG + lane;
    float4 a0 = av[g * 3 + 0];
    float4 a1 = av[g * 3 + 1];
    float4 a2 = av[g * 3 + 2];

#define RL(x) __int_as_float(__builtin_amdgcn_readlane(__float_as_int(x), j))
    for (int c = 0; c < SEG / 64; ++c) {
        float4 b0, b1, b2;
        if (c + 1 < SEG / 64) {           // prefetch next chunk
            const int gn = (g + 64) * 3;
            b0 = av[gn + 0]; b1 = av[gn + 1]; b2 = av[gn + 2];
        }
        // tile-rect vs cull-circle test for this lane's gaussian
        const float ddx = fmaxf(fmaxf(tx0 - a0.x, a0.x - tx1), 0.0f);
        const float ddy = fmaxf(fmaxf(ty0 - a0.y, a0.y - ty1), 0.0f);
        unsigned long long m = __ballot(ddx * ddx + ddy * ddy <= a0.z);
        while (m) {
            const int j = __builtin_ctzll(m);
            m &= (m - 1);
            const float cx = RL(a0.x), cy = RL(a0.y);
            const float A = RL(a0.w), B = RL(a1.x), C = RL(a1.y);
            const float op = RL(a1.z);
            const float cr = RL(a1.w), cgc = RL(a2.x), cb = RL(a2.y);
            const float dx = cx - pxf, dy = cy - pyf;
            const float power = -0.5f * (A * dx * dx + C * dy * dy) - B * dx * dy;
            const float alpha = fminf(0.99f, op * __expf(power));
            const bool keep = (power <= 0.0f) & (alpha >= ALPHA_MIN);
            const float ae = keep ? alpha : 0.0f;
            const float w = ae * T;
            accr = fmaf(w, cr, accr);
            accg = fmaf(w, cgc, accg);
            accb = fmaf(w, cb, accb);
            T *= (1.0f - ae);
        }
        // whole-wave saturated -> done (residual contribution < 1e-4)
        if (__ballot(T >= 1e-4f) == 0ull) break;
        a0 = b0; a1 = b1; a2 = b2; g += 64;
    }
#undef RL

    // merge the 4 z-segments, front to back:
    //   img = sum_s (prod_{s'<s} T_s') * acc_s ,  T = prod_s T_s  (exact)
    part[wave][0][lane] = accr;
    part[wave][1][lane] = accg;
    part[wave][2][lane] = accb;
    part[wave][3][lane] = T;
    __syncthreads();
    if (wave == 0) {
        float R = part[0][0][lane], G = part[0][1][lane], Bc = part[0][2][lane];
        float Tt = part[0][3][lane];
#pragma unroll
        for (int s = 1; s < NSEG; ++s) {
            R  = fmaf(Tt, part[s][0][lane], R);
            G  = fmaf(Tt, part[s][1][lane], G);
            Bc = fmaf(Tt, part[s][2][lane], Bc);
            Tt *= part[s][3][lane];
        }
        const int pix = (tile_y + (lane >> 3)) * IMG_W + tile_x + (lane & 7);
        out[pix]            = fmaf(Tt, bgp[0], R);
        out[pix + NPIX]     = fmaf(Tt, bgp[1], G);
        out[pix + 2 * NPIX] = fmaf(Tt, bgp[2], Bc);
    }
}

// ---------------------------------------------------------------------------
extern "C" void kernel_launch(void* const* d_in, const int* in_sizes, int n_in,
                              void* d_out, int out_size, void* d_ws, size_t ws_size,
                              hipStream_t stream) {
    const float* means  = (const float*)d_in[0];  // (N,3)
    const float* colors = (const float*)d_in[1];  // (N,3)
    const float* opac   = (const float*)d_in[2];  // (N,1)
    const float* cov3   = (const float*)d_in[3];  // (N,6)
    const float* bg     = (const float*)d_in[4];  // (3,)
    float* out = (float*)d_out;  // img (3*128*128) then radii (2048) as float
    float* aos = (float*)d_ws;
    unsigned int* flags = (unsigned int*)((char*)d_ws + 96 * 1024);

    fused_kernel<<<256, 256, 0, stream>>>(means, colors, opac, cov3, bg,
                                          out, aos, flags);
}

// Round 5
// 99.789 us; speedup vs baseline: 1.1572x; 1.0253x over previous
//
#include <hip/hip_runtime.h>
#include <math.h>

#define NG 2048
#define IMG_W 128
#define IMG_H 128
#define NPIX (IMG_W * IMG_H)
#define ALPHA_MIN (1.0f / 255.0f)
#define NSEG 4
#define SEG (NG / NSEG)       // 512 gaussians per z-segment
#define MAGIC 0x13579BDFu     // != 0xAAAAAAAA poison; any init != MAGIC is safe
#define FLAG_STRIDE 16        // dwords: one flag per 64-B cache line

// ws layout:
//   [0, 96K)     : float aos[2048][12] z-sorted params:
//                  px, py, rc2, A, B, C, op, cr, cg, cb, pad, pad
//   [128K, 144K) : uint flags[256 * FLAG_STRIDE] grid-barrier flags,
//                  one per 64-B line (spread -> no hot-line contention)

// ---------------------------------------------------------------------------
// Single regular kernel, 256 blocks x 256 threads (1 block/CU).
// Phase 1: stable ranks (z asc, ties by index == stable argsort) + f64
// projection/conic + z-sorted AoS scatter.  Low-contention manual grid
// barrier (R4's 65536-poller spin congested the coherence fabric ~40us;
// now: 1 wave/block polls, flags cache-line-spread).  Phase 2: render.
__global__ void __launch_bounds__(256) fused_kernel(const float* __restrict__ means,
                                                    const float* __restrict__ colors,
                                                    const float* __restrict__ opac,
                                                    const float* __restrict__ cov3,
                                                    const float* __restrict__ bgp,
                                                    float* __restrict__ out,
                                                    float* __restrict__ aos,
                                                    unsigned int* flags) {
    __shared__ float zs[NG];          // 8 KB: all z values
    __shared__ int   rankv[8];
    __shared__ float part[NSEG][4][64];

    const int t = threadIdx.x;
    const int b = blockIdx.x;

    // ---- Phase 1a: stable rank of this block's 8 gaussians -----------------
    for (int k = t; k < NG; k += 256) zs[k] = means[k * 3 + 2];
    __syncthreads();

    const int grp = t >> 5;             // 0..7: gaussian group
    const int sub = t & 31;
    const int gi  = b * 8 + grp;
    const float zi = zs[gi];
    int cnt = 0;
    // stride-32 scan: lane sub hits bank sub%32 -> 2 lanes/bank = free (m136)
#pragma unroll 8
    for (int k = 0; k < 64; ++k) {
        const int j = sub + 32 * k;
        const float zj = zs[j];
        cnt += (zj < zi || (zj == zi && j < gi)) ? 1 : 0;
    }
#pragma unroll
    for (int d = 16; d; d >>= 1) cnt += __shfl_down(cnt, d, 32);
    if (sub == 0) rankv[grp] = cnt;
    __syncthreads();

    // ---- Phase 1b: projection/conic (f64 keeps ceil() boundaries exact) ----
    if (t < 8) {
        const int i = b * 8 + t;
        const double x = means[i * 3 + 0];
        const double y = means[i * 3 + 1];
        const double z = means[i * 3 + 2];
        const double inv_z = 1.0 / z;
        const double fx = 128.0, fy = 128.0, lim = 0.65;  // W/(2*tanfov), 1.3*tanfov
        const double px = fx * x * inv_z + 64.0;
        const double py = fy * y * inv_z + 64.0;
        double tx = x * inv_z; tx = fmin(fmax(tx, -lim), lim); tx *= z;
        double ty = y * inv_z; ty = fmin(fmax(ty, -lim), lim); ty *= z;
        const double xx = cov3[i * 6 + 0], xy = cov3[i * 6 + 1], xz = cov3[i * 6 + 2];
        const double yy = cov3[i * 6 + 3], yz = cov3[i * 6 + 4], zz = cov3[i * 6 + 5];
        const double J00 = fx * inv_z, J02 = -fx * tx * inv_z * inv_z;
        const double J11 = fy * inv_z, J12 = -fy * ty * inv_z * inv_z;
        const double M00 = J00 * xx + J02 * xz;
        const double M01 = J00 * xy + J02 * yz;
        const double M02 = J00 * xz + J02 * zz;
        const double M11 = J11 * yy + J12 * yz;
        const double M12 = J11 * yz + J12 * zz;
        const double a = M00 * J00 + M02 * J02 + 0.3;
        const double bb = M01 * J11 + M02 * J12;  // cov2[0,1]
        const double c = M11 * J11 + M12 * J12 + 0.3;
        const double det = a * c - bb * bb;
        const double inv_det = 1.0 / det;
        const double mid = 0.5 * (a + c);
        const double lam1 = mid + sqrt(fmax(0.1, mid * mid - det));
        const bool valid = (z > 0.2) && (det > 0.0);
        out[3 * NPIX + i] = valid ? (float)ceil(3.0 * sqrt(lam1)) : 0.0f;

        const float op = opac[i];
        // Conservative cull radius^2: outside it alpha < ALPHA_MIN * e^-0.05
        // guaranteed (d^T Sigma^-1 d >= d^2 / lam1, lam1 >= lambda_max).
        float rc2 = -1.0f;
        if (valid) {
            const double L = log(255.0 * (double)op);
            if (L > 0.0) rc2 = (float)(2.0 * (L + 0.05) * lam1 * 1.0001);
        }
        const int r = rankv[t];
        float4* dst = (float4*)(aos + r * 12);
        dst[0] = make_float4((float)px, (float)py, rc2, (float)(c * inv_det));
        dst[1] = make_float4((float)(-bb * inv_det), (float)(a * inv_det), op,
                             colors[i * 3 + 0]);
        dst[2] = make_float4(colors[i * 3 + 1], colors[i * 3 + 2], 0.0f, 0.0f);
    }

    // ---- Low-contention grid barrier (init-free) ---------------------------
    __syncthreads();                       // block's AoS/radii writes issued
    if (t == 0) {
        __threadfence();                   // agent-scope release of aos writes
        __hip_atomic_store(&flags[b * FLAG_STRIDE], MAGIC, __ATOMIC_RELAXED,
                           __HIP_MEMORY_SCOPE_AGENT);
    }
    if (t < 64) {                          // wave 0 polls: 4 flags per lane
        for (;;) {
            int ok = 1;
#pragma unroll
            for (int k = 0; k < 4; ++k) {
                ok &= (__hip_atomic_load(&flags[(4 * t + k) * FLAG_STRIDE],
                                         __ATOMIC_RELAXED,
                                         __HIP_MEMORY_SCOPE_AGENT) == MAGIC);
            }
            if (__ballot(ok) == ~0ull) break;
            __builtin_amdgcn_s_sleep(4);
        }
    }
    __syncthreads();                       // other waves park here meanwhile
    __threadfence();                       // acquire before reading remote aos

    // ---- Phase 2: render ---------------------------------------------------
    const int lane = t & 63;
    const int wave = t >> 6;
    const int tile_x = (b & 15) * 8;
    const int tile_y = (b >> 4) * 8;
    const float pxf = (float)(tile_x + (lane & 7));
    const float pyf = (float)(tile_y + (lane >> 3));
    const float tx0 = (float)tile_x, tx1 = (float)(tile_x + 7);
    const float ty0 = (float)tile_y, ty1 = (float)(tile_y + 7);

    const float4* __restrict__ av = (const float4*)aos;

    float T = 1.0f, accr = 0.0f, accg = 0.0f, accb = 0.0f;

    int g = wave * SEG + lane;
    float4 a0 = av[g * 3 + 0];
    float4 a1 = av[g * 3 + 1];
    float4 a2 = av[g * 3 + 2];

#define RL(x) __int_as_float(__builtin_amdgcn_readlane(__float_as_int(x), j))
    for (int c = 0; c < SEG / 64; ++c) {
        float4 b0, b1, b2;
        if (c + 1 < SEG / 64) {           // prefetch next chunk
            const int gn = (g + 64) * 3;
            b0 = av[gn + 0]; b1 = av[gn + 1]; b2 = av[gn + 2];
        }
        // tile-rect vs cull-circle test for this lane's gaussian
        const float ddx = fmaxf(fmaxf(tx0 - a0.x, a0.x - tx1), 0.0f);
        const float ddy = fmaxf(fmaxf(ty0 - a0.y, a0.y - ty1), 0.0f);
        unsigned long long m = __ballot(ddx * ddx + ddy * ddy <= a0.z);
        while (m) {
            const int j = __builtin_ctzll(m);
            m &= (m - 1);
            const float cx = RL(a0.x), cy = RL(a0.y);
            const float A = RL(a0.w), B = RL(a1.x), C = RL(a1.y);
            const float op = RL(a1.z);
            const float cr = RL(a1.w), cgc = RL(a2.x), cb = RL(a2.y);
            const float dx = cx - pxf, dy = cy - pyf;
            const float power = -0.5f * (A * dx * dx + C * dy * dy) - B * dx * dy;
            const float alpha = fminf(0.99f, op * __expf(power));
            const bool keep = (power <= 0.0f) & (alpha >= ALPHA_MIN);
            const float ae = keep ? alpha : 0.0f;
            const float w = ae * T;
            accr = fmaf(w, cr, accr);
            accg = fmaf(w, cgc, accg);
            accb = fmaf(w, cb, accb);
            T *= (1.0f - ae);
        }
        // whole-wave saturated -> done (residual contribution < 1e-4)
        if (__ballot(T >= 1e-4f) == 0ull) break;
        a0 = b0; a1 = b1; a2 = b2; g += 64;
    }
#undef RL

    // merge the 4 z-segments, front to back:
    //   img = sum_s (prod_{s'<s} T_s') * acc_s ,  T = prod_s T_s  (exact)
    part[wave][0][lane] = accr;
    part[wave][1][lane] = accg;
    part[wave][2][lane] = accb;
    part[wave][3][lane] = T;
    __syncthreads();
    if (wave == 0) {
        float R = part[0][0][lane], G = part[0][1][lane], Bc = part[0][2][lane];
        float Tt = part[0][3][lane];
#pragma unroll
        for (int s = 1; s < NSEG; ++s) {
            R  = fmaf(Tt, part[s][0][lane], R);
            G  = fmaf(Tt, part[s][1][lane], G);
            Bc = fmaf(Tt, part[s][2][lane], Bc);
            Tt *= part[s][3][lane];
        }
        const int pix = (tile_y + (lane >> 3)) * IMG_W + tile_x + (lane & 7);
        out[pix]            = fmaf(Tt, bgp[0], R);
        out[pix + NPIX]     = fmaf(Tt, bgp[1], G);
        out[pix + 2 * NPIX] = fmaf(Tt, bgp[2], Bc);
    }
}

// ---------------------------------------------------------------------------
extern "C" void kernel_launch(void* const* d_in, const int* in_sizes, int n_in,
                              void* d_out, int out_size, void* d_ws, size_t ws_size,
                              hipStream_t stream) {
    const float* means  = (const float*)d_in[0];  // (N,3)
    const float* colors = (const float*)d_in[1];  // (N,3)
    const float* opac   = (const float*)d_in[2];  // (N,1)
    const float* cov3   = (const float*)d_in[3];  // (N,6)
    const float* bg     = (const float*)d_in[4];  // (3,)
    float* out = (float*)d_out;  // img (3*128*128) then radii (2048) as float
    float* aos = (float*)d_ws;
    unsigned int* flags = (unsigned int*)((char*)d_ws + 128 * 1024);

    fused_kernel<<<256, 256, 0, stream>>>(means, colors, opac, cov3, bg,
                                          out, aos, flags);
}

// Round 6
// 83.317 us; speedup vs baseline: 1.3860x; 1.1977x over previous
//
#include <hip/hip_runtime.h>
#include <math.h>

#define NG 2048
#define IMG_W 128
#define IMG_H 128
#define NPIX (IMG_W * IMG_H)
#define ALPHA_MIN (1.0f / 255.0f)
#define NSEG 4
#define SEG (NG / NSEG)       // 512 gaussians per z-segment

// ws layout: [0, 96K) float aos[2048][12] z-sorted params:
//   px, py, rc2, A, B, C, op, cr, cg, cb, pad, pad
//
// Two regular kernels; the graph edge between them is the grid barrier.
// (R3-R5 showed every in-kernel alternative loses: cooperative launch costs
// ~30us as a graph node; manual flag barriers stall ~40us in device-scope
// fence machinery regardless of poller count / flag spreading.)

// ---------------------------------------------------------------------------
// 64 blocks x 256 threads. Stable rank (z asc, ties by index == stable
// argsort): 8 threads per gaussian scan 256 z's each from LDS (same-address
// broadcast reads - conflict-free), shfl-reduce width 8. Then 32 leader
// threads per block do the f64 projection/conic and scatter the z-sorted AoS.
__global__ void __launch_bounds__(256) prep_kernel(const float* __restrict__ means,
                                                   const float* __restrict__ colors,
                                                   const float* __restrict__ opac,
                                                   const float* __restrict__ cov3,
                                                   float* __restrict__ radii_out,
                                                   float* __restrict__ aos) {
    __shared__ float zs[NG];          // 8 KB
    __shared__ int   rankv[32];

    const int t = threadIdx.x;
    const int b = blockIdx.x;

    for (int k = t; k < NG; k += 256) zs[k] = means[k * 3 + 2];
    __syncthreads();

    const int g   = b * 32 + (t >> 3);  // this thread's gaussian
    const int sub = t & 7;
    const float zg = zs[g];
    int cnt = 0;
#pragma unroll 16
    for (int k = 0; k < 256; ++k) {
        const int j = sub + 8 * k;
        const float zj = zs[j];
        cnt += (zj < zg || (zj == zg && j < g)) ? 1 : 0;
    }
    cnt += __shfl_down(cnt, 4, 8);
    cnt += __shfl_down(cnt, 2, 8);
    cnt += __shfl_down(cnt, 1, 8);
    if (sub == 0) rankv[t >> 3] = cnt;
    __syncthreads();

    if (t < 32) {
        const int i = b * 32 + t;
        const double x = means[i * 3 + 0];
        const double y = means[i * 3 + 1];
        const double z = means[i * 3 + 2];
        const double inv_z = 1.0 / z;
        const double fx = 128.0, fy = 128.0, lim = 0.65;  // W/(2*tanfov), 1.3*tanfov
        const double px = fx * x * inv_z + 64.0;
        const double py = fy * y * inv_z + 64.0;
        double tx = x * inv_z; tx = fmin(fmax(tx, -lim), lim); tx *= z;
        double ty = y * inv_z; ty = fmin(fmax(ty, -lim), lim); ty *= z;
        const double xx = cov3[i * 6 + 0], xy = cov3[i * 6 + 1], xz = cov3[i * 6 + 2];
        const double yy = cov3[i * 6 + 3], yz = cov3[i * 6 + 4], zz = cov3[i * 6 + 5];
        const double J00 = fx * inv_z, J02 = -fx * tx * inv_z * inv_z;
        const double J11 = fy * inv_z, J12 = -fy * ty * inv_z * inv_z;
        const double M00 = J00 * xx + J02 * xz;
        const double M01 = J00 * xy + J02 * yz;
        const double M02 = J00 * xz + J02 * zz;
        const double M11 = J11 * yy + J12 * yz;
        const double M12 = J11 * yz + J12 * zz;
        const double a  = M00 * J00 + M02 * J02 + 0.3;
        const double bb = M01 * J11 + M02 * J12;  // cov2[0,1]
        const double c  = M11 * J11 + M12 * J12 + 0.3;
        const double det = a * c - bb * bb;
        const double inv_det = 1.0 / det;
        const double mid = 0.5 * (a + c);
        const double lam1 = mid + sqrt(fmax(0.1, mid * mid - det));
        const bool valid = (z > 0.2) && (det > 0.0);
        radii_out[i] = valid ? (float)ceil(3.0 * sqrt(lam1)) : 0.0f;

        const float op = opac[i];
        // Conservative cull radius^2: outside it alpha < ALPHA_MIN * e^-0.05
        // guaranteed (d^T Sigma^-1 d >= d^2 / lam1, lam1 >= lambda_max).
        float rc2 = -1.0f;
        if (valid) {
            const double L = log(255.0 * (double)op);
            if (L > 0.0) rc2 = (float)(2.0 * (L + 0.05) * lam1 * 1.0001);
        }
        const int r = rankv[t];
        float4* dst = (float4*)(aos + r * 12);
        dst[0] = make_float4((float)px, (float)py, rc2, (float)(c * inv_det));
        dst[1] = make_float4((float)(-bb * inv_det), (float)(a * inv_det), op,
                             colors[i * 3 + 0]);
        dst[2] = make_float4(colors[i * 3 + 1], colors[i * 3 + 2], 0.0f, 0.0f);
    }
}

// ---------------------------------------------------------------------------
// 256 blocks x 256 threads. Block = one 8x8 pixel tile; each of its 4 waves
// composites a disjoint z-segment of 512 gaussians, then LDS merge:
//   img = sum_s (prod_{s'<s} T_s') * acc_s ,  T = prod_s T_s  (exact).
// Inner loop: per-lane AoS float4 loads (pipelined), ballot over the tile
// cull test, then v_readlane broadcasts -> zero memory ops per hit.
__global__ void __launch_bounds__(256) render_kernel(const float* __restrict__ aos,
                                                     const float* __restrict__ bgp,
                                                     float* __restrict__ out) {
    __shared__ float part[NSEG][4][64];
    const int t = threadIdx.x;
    const int lane = t & 63;
    const int wave = t >> 6;
    const int tile_x = (blockIdx.x & 15) * 8;
    const int tile_y = (blockIdx.x >> 4) * 8;
    const float pxf = (float)(tile_x + (lane & 7));
    const float pyf = (float)(tile_y + (lane >> 3));
    const float tx0 = (float)tile_x, tx1 = (float)(tile_x + 7);
    const float ty0 = (float)tile_y, ty1 = (float)(tile_y + 7);

    const float4* __restrict__ av = (const float4*)aos;

    float T = 1.0f, accr = 0.0f, accg = 0.0f, accb = 0.0f;

    int g = wave * SEG + lane;
    float4 a0 = av[g * 3 + 0];
    float4 a1 = av[g * 3 + 1];
    float4 a2 = av[g * 3 + 2];

#define RL(x) __int_as_float(__builtin_amdgcn_readlane(__float_as_int(x), j))
    for (int c = 0; c < SEG / 64; ++c) {
        float4 b0, b1, b2;
        if (c + 1 < SEG / 64) {           // prefetch next chunk
            const int gn = (g + 64) * 3;
            b0 = av[gn + 0]; b1 = av[gn + 1]; b2 = av[gn + 2];
        }
        // tile-rect vs cull-circle test for this lane's gaussian
        const float ddx = fmaxf(fmaxf(tx0 - a0.x, a0.x - tx1), 0.0f);
        const float ddy = fmaxf(fmaxf(ty0 - a0.y, a0.y - ty1), 0.0f);
        unsigned long long m = __ballot(ddx * ddx + ddy * ddy <= a0.z);
        while (m) {
            const int j = __builtin_ctzll(m);
            m &= (m - 1);
            const float cx = RL(a0.x), cy = RL(a0.y);
            const float A = RL(a0.w), B = RL(a1.x), C = RL(a1.y);
            const float op = RL(a1.z);
            const float cr = RL(a1.w), cgc = RL(a2.x), cb = RL(a2.y);
            const float dx = cx - pxf, dy = cy - pyf;
            const float power = -0.5f * (A * dx * dx + C * dy * dy) - B * dx * dy;
            const float alpha = fminf(0.99f, op * __expf(power));
            const bool keep = (power <= 0.0f) & (alpha >= ALPHA_MIN);
            const float ae = keep ? alpha : 0.0f;
            const float w = ae * T;
            accr = fmaf(w, cr, accr);
            accg = fmaf(w, cgc, accg);
            accb = fmaf(w, cb, accb);
            T *= (1.0f - ae);
        }
        // whole-wave saturated -> done (residual contribution < 1e-4)
        if (__ballot(T >= 1e-4f) == 0ull) break;
        a0 = b0; a1 = b1; a2 = b2; g += 64;
    }
#undef RL

    // merge the 4 z-segments, front to back
    part[wave][0][lane] = accr;
    part[wave][1][lane] = accg;
    part[wave][2][lane] = accb;
    part[wave][3][lane] = T;
    __syncthreads();
    if (wave == 0) {
        float R = part[0][0][lane], G = part[0][1][lane], Bc = part[0][2][lane];
        float Tt = part[0][3][lane];
#pragma unroll
        for (int s = 1; s < NSEG; ++s) {
            R  = fmaf(Tt, part[s][0][lane], R);
            G  = fmaf(Tt, part[s][1][lane], G);
            Bc = fmaf(Tt, part[s][2][lane], Bc);
            Tt *= part[s][3][lane];
        }
        const int pix = (tile_y + (lane >> 3)) * IMG_W + tile_x + (lane & 7);
        out[pix]            = fmaf(Tt, bgp[0], R);
        out[pix + NPIX]     = fmaf(Tt, bgp[1], G);
        out[pix + 2 * NPIX] = fmaf(Tt, bgp[2], Bc);
    }
}

// ---------------------------------------------------------------------------
extern "C" void kernel_launch(void* const* d_in, const int* in_sizes, int n_in,
                              void* d_out, int out_size, void* d_ws, size_t ws_size,
                              hipStream_t stream) {
    const float* means  = (const float*)d_in[0];  // (N,3)
    const float* colors = (const float*)d_in[1];  // (N,3)
    const float* opac   = (const float*)d_in[2];  // (N,1)
    const float* cov3   = (const float*)d_in[3];  // (N,6)
    const float* bg     = (const float*)d_in[4];  // (3,)
    float* out = (float*)d_out;  // img (3*128*128) then radii (2048) as float
    float* aos = (float*)d_ws;

    prep_kernel<<<64, 256, 0, stream>>>(means, colors, opac, cov3,
                                        out + 3 * NPIX, aos);
    render_kernel<<<256, 256, 0, stream>>>(aos, bg, out);
}

// Round 7
// 78.881 us; speedup vs baseline: 1.4640x; 1.0562x over previous
//
#include <hip/hip_runtime.h>
#include <math.h>

#define NG 2048
#define IMG_W 128
#define IMG_H 128
#define NPIX (IMG_W * IMG_H)
#define ALPHA_MIN (1.0f / 255.0f)
#define NSEG 16
#define SEG (NG / NSEG)       // 128 gaussians per z-segment

// ws layout: [0, 96K) float aos[2048][12] z-sorted params:
//   px, py, rc2, A, B, C, op, cr, cg, cb, pad, pad
//
// Two regular kernels; the graph edge between them is the grid barrier.
// (R3-R5: cooperative launch costs ~30us as a graph node; manual flag
// barriers stall ~40us in device-scope fence machinery. R6: graph node
// gaps are ~0, so multi-kernel is free.)

// ---------------------------------------------------------------------------
// 64 blocks x 256 threads. Stable rank (z asc, ties by index == stable
// argsort): 8 threads per gaussian scan 256 z's each from LDS, shfl-reduce
// width 8. Then 32 leader threads per block do the f64 projection/conic and
// scatter the z-sorted AoS.
__global__ void __launch_bounds__(256) prep_kernel(const float* __restrict__ means,
                                                   const float* __restrict__ colors,
                                                   const float* __restrict__ opac,
                                                   const float* __restrict__ cov3,
                                                   float* __restrict__ radii_out,
                                                   float* __restrict__ aos) {
    __shared__ float zs[NG];          // 8 KB
    __shared__ int   rankv[32];

    const int t = threadIdx.x;
    const int b = blockIdx.x;

    for (int k = t; k < NG; k += 256) zs[k] = means[k * 3 + 2];
    __syncthreads();

    const int g   = b * 32 + (t >> 3);  // this thread's gaussian
    const int sub = t & 7;
    const float zg = zs[g];
    int cnt = 0;
#pragma unroll 16
    for (int k = 0; k < 256; ++k) {
        const int j = sub + 8 * k;
        const float zj = zs[j];
        cnt += (zj < zg || (zj == zg && j < g)) ? 1 : 0;
    }
    cnt += __shfl_down(cnt, 4, 8);
    cnt += __shfl_down(cnt, 2, 8);
    cnt += __shfl_down(cnt, 1, 8);
    if (sub == 0) rankv[t >> 3] = cnt;
    __syncthreads();

    if (t < 32) {
        const int i = b * 32 + t;
        const double x = means[i * 3 + 0];
        const double y = means[i * 3 + 1];
        const double z = means[i * 3 + 2];
        const double inv_z = 1.0 / z;
        const double fx = 128.0, fy = 128.0, lim = 0.65;  // W/(2*tanfov), 1.3*tanfov
        const double px = fx * x * inv_z + 64.0;
        const double py = fy * y * inv_z + 64.0;
        double tx = x * inv_z; tx = fmin(fmax(tx, -lim), lim); tx *= z;
        double ty = y * inv_z; ty = fmin(fmax(ty, -lim), lim); ty *= z;
        const double xx = cov3[i * 6 + 0], xy = cov3[i * 6 + 1], xz = cov3[i * 6 + 2];
        const double yy = cov3[i * 6 + 3], yz = cov3[i * 6 + 4], zz = cov3[i * 6 + 5];
        const double J00 = fx * inv_z, J02 = -fx * tx * inv_z * inv_z;
        const double J11 = fy * inv_z, J12 = -fy * ty * inv_z * inv_z;
        const double M00 = J00 * xx + J02 * xz;
        const double M01 = J00 * xy + J02 * yz;
        const double M02 = J00 * xz + J02 * zz;
        const double M11 = J11 * yy + J12 * yz;
        const double M12 = J11 * yz + J12 * zz;
        const double a  = M00 * J00 + M02 * J02 + 0.3;
        const double bb = M01 * J11 + M02 * J12;  // cov2[0,1]
        const double c  = M11 * J11 + M12 * J12 + 0.3;
        const double det = a * c - bb * bb;
        const double inv_det = 1.0 / det;
        const double mid = 0.5 * (a + c);
        const double lam1 = mid + sqrt(fmax(0.1, mid * mid - det));
        const bool valid = (z > 0.2) && (det > 0.0);
        radii_out[i] = valid ? (float)ceil(3.0 * sqrt(lam1)) : 0.0f;

        const float op = opac[i];
        // Conservative cull radius^2: outside it alpha < ALPHA_MIN * e^-0.05
        // guaranteed (d^T Sigma^-1 d >= d^2 / lam1, lam1 >= lambda_max).
        float rc2 = -1.0f;
        if (valid) {
            const double L = log(255.0 * (double)op);
            if (L > 0.0) rc2 = (float)(2.0 * (L + 0.05) * lam1 * 1.0001);
        }
        const int r = rankv[t];
        float4* dst = (float4*)(aos + r * 12);
        dst[0] = make_float4((float)px, (float)py, rc2, (float)(c * inv_det));
        dst[1] = make_float4((float)(-bb * inv_det), (float)(a * inv_det), op,
                             colors[i * 3 + 0]);
        dst[2] = make_float4(colors[i * 3 + 1], colors[i * 3 + 2], 0.0f, 0.0f);
    }
}

// ---------------------------------------------------------------------------
// 256 blocks x 1024 threads (16 waves = 4 waves/SIMD for latency hiding; R6
// showed 1 wave/SIMD leaves the serial per-hit chain latency-exposed).
// Block = one 8x8 pixel tile; each wave composites a disjoint 128-gaussian
// z-segment, then LDS merge (exact):
//   img = sum_s (prod_{s'<s} T_s') * acc_s ,  T = prod_s T_s.
__global__ void __launch_bounds__(1024) render_kernel(const float* __restrict__ aos,
                                                      const float* __restrict__ bgp,
                                                      float* __restrict__ out) {
    __shared__ float part[NSEG][4][64];
    const int t = threadIdx.x;
    const int lane = t & 63;
    const int wave = t >> 6;
    const int tile_x = (blockIdx.x & 15) * 8;
    const int tile_y = (blockIdx.x >> 4) * 8;
    const float pxf = (float)(tile_x + (lane & 7));
    const float pyf = (float)(tile_y + (lane >> 3));
    const float tx0 = (float)tile_x, tx1 = (float)(tile_x + 7);
    const float ty0 = (float)tile_y, ty1 = (float)(tile_y + 7);

    const float4* __restrict__ av = (const float4*)aos;

    float T = 1.0f, accr = 0.0f, accg = 0.0f, accb = 0.0f;

    int g = wave * SEG + lane;
    float4 a0 = av[g * 3 + 0];
    float4 a1 = av[g * 3 + 1];
    float4 a2 = av[g * 3 + 2];

#define RL(x) __int_as_float(__builtin_amdgcn_readlane(__float_as_int(x), j))
#pragma unroll
    for (int c = 0; c < SEG / 64; ++c) {
        float4 b0, b1, b2;
        if (c + 1 < SEG / 64) {           // prefetch next chunk
            const int gn = (g + 64) * 3;
            b0 = av[gn + 0]; b1 = av[gn + 1]; b2 = av[gn + 2];
        }
        // tile-rect vs cull-circle test for this lane's gaussian
        const float ddx = fmaxf(fmaxf(tx0 - a0.x, a0.x - tx1), 0.0f);
        const float ddy = fmaxf(fmaxf(ty0 - a0.y, a0.y - ty1), 0.0f);
        unsigned long long m = __ballot(ddx * ddx + ddy * ddy <= a0.z);
        while (m) {
            const int j = __builtin_ctzll(m);
            m &= (m - 1);
            const float cx = RL(a0.x), cy = RL(a0.y);
            const float A = RL(a0.w), B = RL(a1.x), C = RL(a1.y);
            const float op = RL(a1.z);
            const float cr = RL(a1.w), cgc = RL(a2.x), cb = RL(a2.y);
            const float dx = cx - pxf, dy = cy - pyf;
            const float power = -0.5f * (A * dx * dx + C * dy * dy) - B * dx * dy;
            const float alpha = fminf(0.99f, op * __expf(power));
            const bool keep = (power <= 0.0f) & (alpha >= ALPHA_MIN);
            const float ae = keep ? alpha : 0.0f;
            const float w = ae * T;
            accr = fmaf(w, cr, accr);
            accg = fmaf(w, cgc, accg);
            accb = fmaf(w, cb, accb);
            T *= (1.0f - ae);
        }
        // local-T saturation: dropped weight <= local T (<1e-4) x prefix <= 1e-4
        if (__ballot(T >= 1e-4f) == 0ull) break;
        a0 = b0; a1 = b1; a2 = b2; g += 64;
    }
#undef RL

    // merge the 16 z-segments, front to back (exact reassociation)
    part[wave][0][lane] = accr;
    part[wave][1][lane] = accg;
    part[wave][2][lane] = accb;
    part[wave][3][lane] = T;
    __syncthreads();
    if (wave == 0) {
        float R = part[0][0][lane], G = part[0][1][lane], Bc = part[0][2][lane];
        float Tt = part[0][3][lane];
#pragma unroll
        for (int s = 1; s < NSEG; ++s) {
            R  = fmaf(Tt, part[s][0][lane], R);
            G  = fmaf(Tt, part[s][1][lane], G);
            Bc = fmaf(Tt, part[s][2][lane], Bc);
            Tt *= part[s][3][lane];
        }
        const int pix = (tile_y + (lane >> 3)) * IMG_W + tile_x + (lane & 7);
        out[pix]            = fmaf(Tt, bgp[0], R);
        out[pix + NPIX]     = fmaf(Tt, bgp[1], G);
        out[pix + 2 * NPIX] = fmaf(Tt, bgp[2], Bc);
    }
}

// ---------------------------------------------------------------------------
extern "C" void kernel_launch(void* const* d_in, const int* in_sizes, int n_in,
                              void* d_out, int out_size, void* d_ws, size_t ws_size,
                              hipStream_t stream) {
    const float* means  = (const float*)d_in[0];  // (N,3)
    const float* colors = (const float*)d_in[1];  // (N,3)
    const float* opac   = (const float*)d_in[2];  // (N,1)
    const float* cov3   = (const float*)d_in[3];  // (N,6)
    const float* bg     = (const float*)d_in[4];  // (3,)
    float* out = (float*)d_out;  // img (3*128*128) then radii (2048) as float
    float* aos = (float*)d_ws;

    prep_kernel<<<64, 256, 0, stream>>>(means, colors, opac, cov3,
                                        out + 3 * NPIX, aos);
    render_kernel<<<256, 1024, 0, stream>>>(aos, bg, out);
}